// Round 4
// baseline (957.403 us; speedup 1.0000x reference)
//
#include <hip/hip_runtime.h>
#include <math.h>

#define NNODES 50000
#define NEDGES 800000
#define DIN    256
#define DHID   128
#define NCLS   40

#define BW   128                 // dst values per bucket
#define NBK  391                 // ceil(NNODES / BW)
#define CAP  6144                // LDS col capacity per bucket (mean 2048, sd ~45)

// ---------------- fc1: x1 = relu(X @ W1 + b1), 16 nodes/block, k by 4 --------
__global__ __launch_bounds__(256) void fc1_kernel(
    const float* __restrict__ X, const float* __restrict__ W1,
    const float* __restrict__ b1, float* __restrict__ x1)
{
  __shared__ float Xs[16][DIN];      // 16 KB
  const int tid   = threadIdx.x;
  const int node0 = blockIdx.x * 16;

  const float4* Xv  = (const float4*)(X + (size_t)node0 * DIN);
  float4*       Xsv = (float4*)(&Xs[0][0]);
#pragma unroll
  for (int t = 0; t < 4; ++t) Xsv[tid + t * 256] = Xv[tid + t * 256];
  __syncthreads();

  const int h  = tid & 127;
  const int tm = tid >> 7;           // 0..1 -> node groups of 8
  float acc[8];
#pragma unroll
  for (int r = 0; r < 8; ++r) acc[r] = 0.f;

  for (int k = 0; k < DIN; k += 4) {
    const float w0 = W1[(k + 0) * DHID + h];
    const float w1 = W1[(k + 1) * DHID + h];
    const float w2 = W1[(k + 2) * DHID + h];
    const float w3 = W1[(k + 3) * DHID + h];
#pragma unroll
    for (int r = 0; r < 8; ++r) {
      const float4 xv = *(const float4*)&Xs[tm * 8 + r][k];   // ds_read_b128 broadcast
      acc[r] += xv.x * w0 + xv.y * w1 + xv.z * w2 + xv.w * w3;
    }
  }
  const float bb = b1[h];
#pragma unroll
  for (int r = 0; r < 8; ++r) {
    float v = acc[r] + bb;
    x1[(size_t)(node0 + tm * 8 + r) * DHID + h] = v > 0.f ? v : 0.f;
  }
}

// ---------------- fc2: out = x3 @ W2 + b2, 8 nodes/block (320 thr) -----------
__global__ __launch_bounds__(320) void fc2_kernel(
    const float* __restrict__ x3, const float* __restrict__ W2,
    const float* __restrict__ b2, float* __restrict__ out)
{
  __shared__ float Xs[8][DHID];      // 4 KB
  const int tid   = threadIdx.x;
  const int node0 = blockIdx.x * 8;
  for (int idx = tid; idx < 8 * DHID; idx += 320)
    Xs[idx >> 7][idx & 127] = x3[(size_t)node0 * DHID + idx];
  __syncthreads();

  const int ns = tid / NCLS;         // 0..7
  const int c  = tid - ns * NCLS;    // 0..39
  float acc = b2[c];
#pragma unroll 8
  for (int k = 0; k < DHID; ++k) acc += Xs[ns][k] * W2[k * NCLS + c];
  out[(size_t)(node0 + ns) * NCLS + c] = acc;
}

// ---------------- CSR build, bucketized --------------------------------------
// K1: coarse histogram over 2*391 buckets, LDS-aggregated
__global__ __launch_bounds__(256) void bucket_hist_kernel(
    const int* __restrict__ dst1, const int* __restrict__ dst2,
    int* __restrict__ bcnt /* [2*NBK] */)
{
  __shared__ int h[2 * NBK];
  for (int i = threadIdx.x; i < 2 * NBK; i += 256) h[i] = 0;
  __syncthreads();
  const int stride = gridDim.x * 256;
  for (int i = blockIdx.x * 256 + threadIdx.x; i < 2 * NEDGES; i += stride) {
    if (i < NEDGES) atomicAdd(&h[dst1[i] >> 7], 1);
    else            atomicAdd(&h[NBK + (dst2[i - NEDGES] >> 7)], 1);
  }
  __syncthreads();
  for (int i = threadIdx.x; i < 2 * NBK; i += 256)
    if (h[i]) atomicAdd(&bcnt[i], h[i]);
}

// K2: scan bucket counts per view -> bucket offsets, init cursors, rp[N]
__global__ __launch_bounds__(512) void scan_buckets_kernel(
    const int* __restrict__ bcnt, int* __restrict__ boff /* [2*(NBK+1)] */,
    int* __restrict__ bcur /* [2*NBK] */,
    int* __restrict__ rp1, int* __restrict__ rp2)
{
  __shared__ int sm[NBK + 1];
  const int tid = threadIdx.x;
  for (int v = 0; v < 2; ++v) {
    if (tid == 0) sm[0] = 0;
    if (tid < NBK) sm[tid + 1] = bcnt[v * NBK + tid];
    __syncthreads();
    for (int off = 1; off < NBK; off <<= 1) {
      int t = (tid < NBK && tid + 1 >= off) ? sm[tid + 1 - off] : 0;
      __syncthreads();
      if (tid < NBK && tid + 1 >= off) sm[tid + 1] += t;
      __syncthreads();
    }
    if (tid <= NBK) boff[v * (NBK + 1) + tid] = sm[tid];
    if (tid < NBK)  bcur[v * NBK + tid] = sm[tid];
    if (tid == 0)   (v ? rp2 : rp1)[NNODES] = sm[NBK];
    __syncthreads();
  }
}

// K3: append (src,dst) pairs to per-bucket staging (write frontier ~50 KB -> L2)
__global__ __launch_bounds__(256) void append_kernel(
    const int* __restrict__ src1, const int* __restrict__ dst1,
    const int* __restrict__ src2, const int* __restrict__ dst2,
    int* __restrict__ bcur, int2* __restrict__ st1, int2* __restrict__ st2)
{
  const int stride = gridDim.x * 256;
  for (int i = blockIdx.x * 256 + threadIdx.x; i < 2 * NEDGES; i += stride) {
    if (i < NEDGES) {
      const int s = src1[i], d = dst1[i];
      const int pos = atomicAdd(&bcur[d >> 7], 1);
      st1[pos] = make_int2(s, d);
    } else {
      const int j = i - NEDGES;
      const int s = src2[j], d = dst2[j];
      const int pos = atomicAdd(&bcur[NBK + (d >> 7)], 1);
      st2[pos] = make_int2(s, d);
    }
  }
}

// K4: per bucket: degrees -> rp, place srcs in LDS, sort segments (determinism),
//     coalesced col write.
__global__ __launch_bounds__(256) void build_buckets_kernel(
    const int2* __restrict__ st1, const int2* __restrict__ st2,
    const int* __restrict__ boff,
    int* __restrict__ rp1, int* __restrict__ rp2,
    int* __restrict__ col1, int* __restrict__ col2)
{
  const int bid = blockIdx.x;
  const int v   = bid >= NBK;
  const int b   = v ? bid - NBK : bid;
  const int2* __restrict__ st = v ? st2 : st1;
  int* __restrict__ rp  = v ? rp2 : rp1;
  int* __restrict__ col = v ? col2 : col1;
  const int tid = threadIdx.x;

  const int off0   = boff[v * (NBK + 1) + b];
  const int cnt    = boff[v * (NBK + 1) + b + 1] - off0;
  const int base_d = b * BW;
  const int nd     = (NNODES - base_d < BW) ? (NNODES - base_d) : BW;

  __shared__ int deg[BW];
  __shared__ int loff[BW + 1];
  __shared__ int cur[BW];
  __shared__ int lcol[CAP];

  if (tid < BW) deg[tid] = 0;
  __syncthreads();
  for (int j = tid; j < cnt; j += 256)
    atomicAdd(&deg[st[off0 + j].y - base_d], 1);
  __syncthreads();

  // exclusive scan deg -> loff (loff[d] = local segment base, loff[BW] = cnt)
  if (tid == 0) loff[0] = 0;
  if (tid < BW) loff[tid + 1] = deg[tid];
  __syncthreads();
  for (int off = 1; off < BW; off <<= 1) {
    int t = (tid < BW && tid + 1 >= off) ? loff[tid + 1 - off] : 0;
    __syncthreads();
    if (tid < BW && tid + 1 >= off) loff[tid + 1] += t;
    __syncthreads();
  }
  if (tid < nd) rp[base_d + tid] = off0 + loff[tid];
  if (tid < BW) cur[tid] = loff[tid];
  __syncthreads();

  if (cnt <= CAP) {
    for (int j = tid; j < cnt; j += 256) {
      const int2 p = st[off0 + j];
      const int k = atomicAdd(&cur[p.y - base_d], 1);
      lcol[k] = p.x;
    }
    __syncthreads();
    if (tid < nd) {                   // sort own segment ascending (in LDS)
      const int s0 = loff[tid], s1 = s0 + deg[tid];
      for (int a = s0 + 1; a < s1; ++a) {
        const int key = lcol[a];
        int c = a - 1;
        while (c >= s0 && lcol[c] > key) { lcol[c + 1] = lcol[c]; --c; }
        lcol[c + 1] = key;
      }
    }
    __syncthreads();
    for (int j = tid; j < cnt; j += 256) col[off0 + j] = lcol[j];
  } else {                            // overflow fallback (never for random data)
    for (int j = tid; j < cnt; j += 256) {
      const int2 p = st[off0 + j];
      const int k = atomicAdd(&cur[p.y - base_d], 1);
      col[off0 + k] = p.x;
    }
    __syncthreads();
    if (tid < nd) {
      const int s0 = off0 + loff[tid], s1 = s0 + deg[tid];
      for (int a = s0 + 1; a < s1; ++a) {
        const int key = col[a];
        int c = a - 1;
        while (c >= s0 && col[c] > key) { col[c + 1] = col[c]; --c; }
        col[c + 1] = key;
      }
    }
  }
}

// ---------------- inverse row norms ------------------------------------------
__global__ __launch_bounds__(256) void rownorm_inv_kernel(
    const float* __restrict__ x, float* __restrict__ inv, int n)
{
  const int wid  = (blockIdx.x * blockDim.x + threadIdx.x) >> 6;
  const int lane = threadIdx.x & 63;
  if (wid >= n) return;
  float2 v = *(const float2*)(x + (size_t)wid * DHID + lane * 2);
  float ss = v.x * v.x + v.y * v.y;
#pragma unroll
  for (int off = 32; off; off >>= 1) ss += __shfl_xor(ss, off);
  if (lane == 0) inv[wid] = 1.0f / fmaxf(sqrtf(ss), 1e-12f);
}

// ---------------- AGNN layer: wave/node, 4 edges in flight (16-lane groups) --
// softmax shift-invariance: w = exp(e) directly (|e| <= |beta|), identical to
// the reference's max-subtracted softmax up to fp32 rounding.
__global__ __launch_bounds__(256) void agnn_layer_kernel(
    const float* __restrict__ x, const float* __restrict__ inv,
    const int* __restrict__ rp1, const int* __restrict__ col1,
    const int* __restrict__ rp2, const int* __restrict__ col2,
    const float* __restrict__ beta_p, const float* __restrict__ order_attn,
    float* __restrict__ y_out, int n)
{
  const int wid  = (blockIdx.x * blockDim.x + threadIdx.x) >> 6;
  if (wid >= n) return;
  const int lane = threadIdx.x & 63;
  const int grp  = lane >> 4;        // 0..3  : which edge of the 4 in flight
  const int sub  = lane & 15;        // 0..15 : 8 dims each -> 128 dims

  const float beta = beta_p[0];
  const float bi   = beta * inv[wid];

  const float* xd_p = x + (size_t)wid * DHID + sub * 8;
  const float4 xd0 = *(const float4*)(xd_p);
  const float4 xd1 = *(const float4*)(xd_p + 4);

  float acc[8];
#pragma unroll
  for (int k = 0; k < 8; ++k) acc[k] = 0.f;

#pragma unroll
  for (int view = 0; view < 2; ++view) {
    const int*  rp   = view ? rp2 : rp1;
    const int*  col  = view ? col2 : col1;
    const float coef = order_attn[view];
    const int beg = rp[wid], end = rp[wid + 1];

    float s = 0.f;
    float yv[8];
#pragma unroll
    for (int k = 0; k < 8; ++k) yv[k] = 0.f;

    for (int j = beg + grp; j < end; j += 4) {
      const int   sa  = col[j];
      const float isa = inv[sa];
      const float* xs_p = x + (size_t)sa * DHID + sub * 8;
      const float4 a0 = *(const float4*)(xs_p);
      const float4 a1 = *(const float4*)(xs_p + 4);

      float d = a0.x * xd0.x + a0.y * xd0.y + a0.z * xd0.z + a0.w * xd0.w
              + a1.x * xd1.x + a1.y * xd1.y + a1.z * xd1.z + a1.w * xd1.w;
      d += __shfl_xor(d, 1);
      d += __shfl_xor(d, 2);
      d += __shfl_xor(d, 4);
      d += __shfl_xor(d, 8);

      const float w = __expf(bi * isa * d);
      s += w;
      yv[0] += w * a0.x; yv[1] += w * a0.y; yv[2] += w * a0.z; yv[3] += w * a0.w;
      yv[4] += w * a1.x; yv[5] += w * a1.y; yv[6] += w * a1.z; yv[7] += w * a1.w;
    }

    // merge the 4 group-partials (groups differ in lane bits 4..5)
    s += __shfl_xor(s, 16);
    s += __shfl_xor(s, 32);
#pragma unroll
    for (int k = 0; k < 8; ++k) {
      yv[k] += __shfl_xor(yv[k], 16);
      yv[k] += __shfl_xor(yv[k], 32);
    }
    if (end > beg) {
      const float r = coef / fmaxf(s, 1e-12f);
#pragma unroll
      for (int k = 0; k < 8; ++k) acc[k] += r * yv[k];
    }
  }

  if (grp == 0) {
    float* yp = y_out + (size_t)wid * DHID + sub * 8;
    *(float4*)(yp)     = make_float4(acc[0], acc[1], acc[2], acc[3]);
    *(float4*)(yp + 4) = make_float4(acc[4], acc[5], acc[6], acc[7]);
  }
}

// ---------------- launcher ----------------------------------------------------
extern "C" void kernel_launch(void* const* d_in, const int* in_sizes, int n_in,
                              void* d_out, int out_size, void* d_ws, size_t ws_size,
                              hipStream_t stream)
{
  const float* X          = (const float*)d_in[0];
  const int*   src1       = (const int*)d_in[1];
  const int*   dst1       = (const int*)d_in[2];
  const int*   src2       = (const int*)d_in[3];
  const int*   dst2       = (const int*)d_in[4];
  const float* order_attn = (const float*)d_in[5];
  const float* W1         = (const float*)d_in[6];
  const float* b1         = (const float*)d_in[7];
  const float* W2         = (const float*)d_in[8];
  const float* b2         = (const float*)d_in[9];
  const float* beta1      = (const float*)d_in[10];
  const float* beta2      = (const float*)d_in[11];
  float*       out        = (float*)d_out;

  char*  ws  = (char*)d_ws;
  size_t off = 0;
  auto alloc = [&](size_t bytes) -> void* {
    void* p = ws + off;
    off += (bytes + 255) & ~size_t(255);
    return p;
  };
  float* x1   = (float*)alloc((size_t)NNODES * DHID * 4);
  float* x2   = (float*)alloc((size_t)NNODES * DHID * 4);
  float* inv  = (float*)alloc((size_t)NNODES * 4);
  int*   rp1  = (int*)alloc((size_t)(NNODES + 1) * 4);
  int*   rp2  = (int*)alloc((size_t)(NNODES + 1) * 4);
  int*   col1 = (int*)alloc((size_t)NEDGES * 4);
  int*   col2 = (int*)alloc((size_t)NEDGES * 4);
  int*   bcnt = (int*)alloc((size_t)2 * NBK * 4);
  int*   boff = (int*)alloc((size_t)2 * (NBK + 1) * 4);
  int*   bcur = (int*)alloc((size_t)2 * NBK * 4);
  // staging overlays x2: st1+st2 = 12.8 MB <= 25.6 MB, dead before agnn writes x2
  int2*  st1  = (int2*)x2;
  int2*  st2  = st1 + NEDGES;
  float* x3   = x1;   // x1 dead after layer1 -> reuse

  const int WB = (NNODES + 3) / 4;   // 4 waves (nodes) per 256-thread block

  // CSR for both views (reused by both layers); segments sorted in LDS so the
  // build is fully deterministic despite atomic ordering.
  hipMemsetAsync(bcnt, 0, (size_t)2 * NBK * 4, stream);
  bucket_hist_kernel<<<1024, 256, 0, stream>>>(dst1, dst2, bcnt);
  scan_buckets_kernel<<<1, 512, 0, stream>>>(bcnt, boff, bcur, rp1, rp2);
  append_kernel<<<1024, 256, 0, stream>>>(src1, dst1, src2, dst2, bcur, st1, st2);
  build_buckets_kernel<<<2 * NBK, 256, 0, stream>>>(st1, st2, boff,
                                                    rp1, rp2, col1, col2);

  fc1_kernel<<<NNODES / 16, 256, 0, stream>>>(X, W1, b1, x1);

  rownorm_inv_kernel<<<WB, 256, 0, stream>>>(x1, inv, NNODES);
  agnn_layer_kernel<<<WB, 256, 0, stream>>>(x1, inv, rp1, col1, rp2, col2,
                                            beta1, order_attn, x2, NNODES);
  rownorm_inv_kernel<<<WB, 256, 0, stream>>>(x2, inv, NNODES);
  agnn_layer_kernel<<<WB, 256, 0, stream>>>(x2, inv, rp1, col1, rp2, col2,
                                            beta2, order_attn, x3, NNODES);

  fc2_kernel<<<NNODES / 8, 320, 0, stream>>>(x3, W2, b2, out);
}

// Round 5
// 579.565 us; speedup vs baseline: 1.6519x; 1.6519x over previous
//
#include <hip/hip_runtime.h>
#include <math.h>

#define NNODES 50000
#define NEDGES 800000
#define DIN    256
#define DHID   128
#define NCLS   40

#define BW    128                    // dst values per bucket
#define NBK   391                    // ceil(NNODES / BW)
#define CAP   6144                   // LDS col capacity per bucket (mean 2048, sd ~45)
#define PPART 128                    // partition blocks per view
#define CHUNK 6250                   // NEDGES / PPART
#define HLEN  (2 * NBK * PPART)      // 100096
#define CH2   ((HLEN + 1023) / 1024) // 98

// ---------------- fc1: x1 = relu(X @ W1 + b1) + fused row-norm ---------------
__global__ __launch_bounds__(256) void fc1_kernel(
    const float* __restrict__ X, const float* __restrict__ W1,
    const float* __restrict__ b1, float* __restrict__ x1,
    float* __restrict__ inv1)
{
  __shared__ float Xs[16][DIN];      // 16 KB
  __shared__ float ssrow[16];
  const int tid   = threadIdx.x;
  const int node0 = blockIdx.x * 16;

  if (tid < 16) ssrow[tid] = 0.f;
  const float4* Xv  = (const float4*)(X + (size_t)node0 * DIN);
  float4*       Xsv = (float4*)(&Xs[0][0]);
#pragma unroll
  for (int t = 0; t < 4; ++t) Xsv[tid + t * 256] = Xv[tid + t * 256];
  __syncthreads();

  const int h  = tid & 127;
  const int tm = tid >> 7;           // 0..1 -> node groups of 8
  float acc[8];
#pragma unroll
  for (int r = 0; r < 8; ++r) acc[r] = 0.f;

  for (int k = 0; k < DIN; k += 4) {
    const float w0 = W1[(k + 0) * DHID + h];
    const float w1 = W1[(k + 1) * DHID + h];
    const float w2 = W1[(k + 2) * DHID + h];
    const float w3 = W1[(k + 3) * DHID + h];
#pragma unroll
    for (int r = 0; r < 8; ++r) {
      const float4 xv = *(const float4*)&Xs[tm * 8 + r][k];   // ds_read_b128 broadcast
      acc[r] += xv.x * w0 + xv.y * w1 + xv.z * w2 + xv.w * w3;
    }
  }
  const float bb   = b1[h];
  const int   lane = tid & 63;
#pragma unroll
  for (int r = 0; r < 8; ++r) {
    float v = acc[r] + bb;
    v = v > 0.f ? v : 0.f;
    x1[(size_t)(node0 + tm * 8 + r) * DHID + h] = v;
    float q = v * v;                 // fused norm: reduce over 128 cols (2 waves)
#pragma unroll
    for (int off = 32; off; off >>= 1) q += __shfl_xor(q, off);
    if (lane == 0) atomicAdd(&ssrow[tm * 8 + r], q);   // exactly 2 adds/row: commutative
  }
  __syncthreads();
  if (tid < 16) inv1[node0 + tid] = 1.0f / fmaxf(sqrtf(ssrow[tid]), 1e-12f);
}

// ---------------- fc2: out = x3 @ W2 + b2, 8 nodes/block (320 thr) -----------
__global__ __launch_bounds__(320) void fc2_kernel(
    const float* __restrict__ x3, const float* __restrict__ W2,
    const float* __restrict__ b2, float* __restrict__ out)
{
  __shared__ float Xs[8][DHID];      // 4 KB
  const int tid   = threadIdx.x;
  const int node0 = blockIdx.x * 8;
  for (int idx = tid; idx < 8 * DHID; idx += 320)
    Xs[idx >> 7][idx & 127] = x3[(size_t)node0 * DHID + idx];
  __syncthreads();

  const int ns = tid / NCLS;         // 0..7
  const int c  = tid - ns * NCLS;    // 0..39
  float acc = b2[c];
#pragma unroll 8
  for (int k = 0; k < DHID; ++k) acc += Xs[ns][k] * W2[k * NCLS + c];
  out[(size_t)(node0 + ns) * NCLS + c] = acc;
}

// ---------------- CSR build: deterministic two-pass multi-split --------------
// K1: per-(view,block) LDS histogram of a private edge chunk -> H[v][bkt][blk]
__global__ __launch_bounds__(256) void hist_part_kernel(
    const int* __restrict__ dst1, const int* __restrict__ dst2,
    int* __restrict__ H)
{
  const int bid = blockIdx.x;
  const int v   = bid >= PPART;
  const int p   = v ? bid - PPART : bid;
  const int* __restrict__ dst = v ? dst2 : dst1;

  __shared__ int hist[NBK];
  for (int i = threadIdx.x; i < NBK; i += 256) hist[i] = 0;
  __syncthreads();
  const int beg = p * CHUNK;
  const int end = (beg + CHUNK < NEDGES) ? beg + CHUNK : NEDGES;
  for (int j = beg + threadIdx.x; j < end; j += 256)
    atomicAdd(&hist[dst[j] >> 7], 1);
  __syncthreads();
  for (int i = threadIdx.x; i < NBK; i += 256)
    H[(v * NBK + i) * PPART + p] = hist[i];
}

// K2: exclusive scan of H (both views, global positions) + bucket bases
__global__ __launch_bounds__(1024) void scan_h_kernel(
    int* __restrict__ H, int* __restrict__ boffG)
{
  __shared__ int sm[1024];
  const int tid  = threadIdx.x;
  const int base = tid * CH2;
  const int end  = (base + CH2 < HLEN) ? base + CH2 : HLEN;
  int s = 0;
  for (int i = base; i < end; ++i) s += H[i];
  sm[tid] = s;
  __syncthreads();
  for (int off = 1; off < 1024; off <<= 1) {
    int t = (tid >= off) ? sm[tid - off] : 0;
    __syncthreads();
    sm[tid] += t;
    __syncthreads();
  }
  int run = sm[tid] - s;
  for (int i = base; i < end; ++i) {
    const int c = H[i];
    H[i] = run;
    if ((i & (PPART - 1)) == 0) boffG[i / PPART] = run;
    run += c;
  }
  if (tid == 0) boffG[2 * NBK] = 2 * NEDGES;
}

// K3: place edges at exact positions (LDS cursors only; writes cluster ~128B)
__global__ __launch_bounds__(256) void scatter_part_kernel(
    const int* __restrict__ src1, const int* __restrict__ dst1,
    const int* __restrict__ src2, const int* __restrict__ dst2,
    const int* __restrict__ H, int2* __restrict__ st)
{
  const int bid = blockIdx.x;
  const int v   = bid >= PPART;
  const int p   = v ? bid - PPART : bid;
  const int* __restrict__ src = v ? src2 : src1;
  const int* __restrict__ dst = v ? dst2 : dst1;

  __shared__ int lcur[NBK];
  for (int i = threadIdx.x; i < NBK; i += 256)
    lcur[i] = H[(v * NBK + i) * PPART + p];
  __syncthreads();
  const int beg = p * CHUNK;
  const int end = (beg + CHUNK < NEDGES) ? beg + CHUNK : NEDGES;
  for (int j = beg + threadIdx.x; j < end; j += 256) {
    const int s = src[j], d = dst[j];
    const int k = atomicAdd(&lcur[d >> 7], 1);
    st[k] = make_int2(s, d);
  }
}

// K4: per bucket: degrees -> rp, place srcs in LDS, sort segments (determinism),
//     coalesced col write.
__global__ __launch_bounds__(256) void build_buckets_kernel(
    const int2* __restrict__ st, const int* __restrict__ boffG,
    int* __restrict__ rp1, int* __restrict__ rp2,
    int* __restrict__ col1, int* __restrict__ col2)
{
  const int bid = blockIdx.x;
  const int v   = bid >= NBK;
  const int b   = v ? bid - NBK : bid;
  int* __restrict__ rp  = v ? rp2 : rp1;
  int* __restrict__ col = v ? col2 : col1;
  const int tid = threadIdx.x;

  const int off0G  = boffG[bid];
  const int cnt    = boffG[bid + 1] - off0G;
  const int off0   = off0G - v * NEDGES;    // view-local offset
  const int base_d = b * BW;
  const int nd     = (NNODES - base_d < BW) ? (NNODES - base_d) : BW;

  __shared__ int deg[BW];
  __shared__ int loff[BW + 1];
  __shared__ int cur[BW];
  __shared__ int lcol[CAP];

  if (tid < BW) deg[tid] = 0;
  __syncthreads();
  for (int j = tid; j < cnt; j += 256)
    atomicAdd(&deg[st[off0G + j].y - base_d], 1);
  __syncthreads();

  if (tid == 0) loff[0] = 0;
  if (tid < BW) loff[tid + 1] = deg[tid];
  __syncthreads();
  for (int off = 1; off < BW; off <<= 1) {
    int t = (tid < BW && tid + 1 >= off) ? loff[tid + 1 - off] : 0;
    __syncthreads();
    if (tid < BW && tid + 1 >= off) loff[tid + 1] += t;
    __syncthreads();
  }
  if (tid < nd) rp[base_d + tid] = off0 + loff[tid];
  if (tid == 0 && b == NBK - 1) rp[NNODES] = NEDGES;
  if (tid < BW) cur[tid] = loff[tid];
  __syncthreads();

  if (cnt <= CAP) {
    for (int j = tid; j < cnt; j += 256) {
      const int2 pr = st[off0G + j];
      const int k = atomicAdd(&cur[pr.y - base_d], 1);
      lcol[k] = pr.x;
    }
    __syncthreads();
    if (tid < nd) {                   // sort own segment ascending (in LDS)
      const int s0 = loff[tid], s1 = s0 + deg[tid];
      for (int a = s0 + 1; a < s1; ++a) {
        const int key = lcol[a];
        int c = a - 1;
        while (c >= s0 && lcol[c] > key) { lcol[c + 1] = lcol[c]; --c; }
        lcol[c + 1] = key;
      }
    }
    __syncthreads();
    for (int j = tid; j < cnt; j += 256) col[off0 + j] = lcol[j];
  } else {                            // overflow fallback (never for random data)
    for (int j = tid; j < cnt; j += 256) {
      const int2 pr = st[off0G + j];
      const int k = atomicAdd(&cur[pr.y - base_d], 1);
      col[off0 + k] = pr.x;
    }
    __syncthreads();
    if (tid < nd) {
      const int s0 = off0 + loff[tid], s1 = s0 + deg[tid];
      for (int a = s0 + 1; a < s1; ++a) {
        const int key = col[a];
        int c = a - 1;
        while (c >= s0 && col[c] > key) { col[c + 1] = col[c]; --c; }
        col[c + 1] = key;
      }
    }
  }
}

// ---------------- AGNN layer: wave/node, 4 edges in flight (16-lane groups) --
// softmax shift-invariance: w = exp(e) directly (|e| <= |beta|), identical to
// the reference's max-subtracted softmax up to fp32 rounding. Optionally fuses
// the output row-norm (inv_out) for the next layer.
__global__ __launch_bounds__(256) void agnn_layer_kernel(
    const float* __restrict__ x, const float* __restrict__ inv,
    const int* __restrict__ rp1, const int* __restrict__ col1,
    const int* __restrict__ rp2, const int* __restrict__ col2,
    const float* __restrict__ beta_p, const float* __restrict__ order_attn,
    float* __restrict__ y_out, float* __restrict__ inv_out, int n)
{
  const int wid  = (blockIdx.x * blockDim.x + threadIdx.x) >> 6;
  if (wid >= n) return;
  const int lane = threadIdx.x & 63;
  const int grp  = lane >> 4;        // 0..3  : which edge of the 4 in flight
  const int sub  = lane & 15;        // 0..15 : 8 dims each -> 128 dims

  const float beta = beta_p[0];
  const float bi   = beta * inv[wid];

  const float* xd_p = x + (size_t)wid * DHID + sub * 8;
  const float4 xd0 = *(const float4*)(xd_p);
  const float4 xd1 = *(const float4*)(xd_p + 4);

  float acc[8];
#pragma unroll
  for (int k = 0; k < 8; ++k) acc[k] = 0.f;

#pragma unroll
  for (int view = 0; view < 2; ++view) {
    const int*  rp   = view ? rp2 : rp1;
    const int*  col  = view ? col2 : col1;
    const float coef = order_attn[view];
    const int beg = rp[wid], end = rp[wid + 1];

    float s = 0.f;
    float yv[8];
#pragma unroll
    for (int k = 0; k < 8; ++k) yv[k] = 0.f;

    for (int j = beg + grp; j < end; j += 4) {
      const int   sa  = col[j];
      const float isa = inv[sa];
      const float* xs_p = x + (size_t)sa * DHID + sub * 8;
      const float4 a0 = *(const float4*)(xs_p);
      const float4 a1 = *(const float4*)(xs_p + 4);

      float d = a0.x * xd0.x + a0.y * xd0.y + a0.z * xd0.z + a0.w * xd0.w
              + a1.x * xd1.x + a1.y * xd1.y + a1.z * xd1.z + a1.w * xd1.w;
      d += __shfl_xor(d, 1);
      d += __shfl_xor(d, 2);
      d += __shfl_xor(d, 4);
      d += __shfl_xor(d, 8);

      const float w = __expf(bi * isa * d);
      s += w;
      yv[0] += w * a0.x; yv[1] += w * a0.y; yv[2] += w * a0.z; yv[3] += w * a0.w;
      yv[4] += w * a1.x; yv[5] += w * a1.y; yv[6] += w * a1.z; yv[7] += w * a1.w;
    }

    // merge the 4 group-partials (groups differ in lane bits 4..5)
    s += __shfl_xor(s, 16);
    s += __shfl_xor(s, 32);
#pragma unroll
    for (int k = 0; k < 8; ++k) {
      yv[k] += __shfl_xor(yv[k], 16);
      yv[k] += __shfl_xor(yv[k], 32);
    }
    if (end > beg) {
      const float r = coef / fmaxf(s, 1e-12f);
#pragma unroll
      for (int k = 0; k < 8; ++k) acc[k] += r * yv[k];
    }
  }

  if (inv_out) {                     // fused row-norm of the output row
    float ss = 0.f;
#pragma unroll
    for (int k = 0; k < 8; ++k) ss += acc[k] * acc[k];
    ss += __shfl_xor(ss, 1);
    ss += __shfl_xor(ss, 2);
    ss += __shfl_xor(ss, 4);
    ss += __shfl_xor(ss, 8);
    if (lane == 0) inv_out[wid] = 1.0f / fmaxf(sqrtf(ss), 1e-12f);
  }

  if (grp == 0) {
    float* yp = y_out + (size_t)wid * DHID + sub * 8;
    *(float4*)(yp)     = make_float4(acc[0], acc[1], acc[2], acc[3]);
    *(float4*)(yp + 4) = make_float4(acc[4], acc[5], acc[6], acc[7]);
  }
}

// ---------------- launcher ----------------------------------------------------
extern "C" void kernel_launch(void* const* d_in, const int* in_sizes, int n_in,
                              void* d_out, int out_size, void* d_ws, size_t ws_size,
                              hipStream_t stream)
{
  const float* X          = (const float*)d_in[0];
  const int*   src1       = (const int*)d_in[1];
  const int*   dst1       = (const int*)d_in[2];
  const int*   src2       = (const int*)d_in[3];
  const int*   dst2       = (const int*)d_in[4];
  const float* order_attn = (const float*)d_in[5];
  const float* W1         = (const float*)d_in[6];
  const float* b1         = (const float*)d_in[7];
  const float* W2         = (const float*)d_in[8];
  const float* b2         = (const float*)d_in[9];
  const float* beta1      = (const float*)d_in[10];
  const float* beta2      = (const float*)d_in[11];
  float*       out        = (float*)d_out;

  char*  ws  = (char*)d_ws;
  size_t off = 0;
  auto alloc = [&](size_t bytes) -> void* {
    void* p = ws + off;
    off += (bytes + 255) & ~size_t(255);
    return p;
  };
  float* x1    = (float*)alloc((size_t)NNODES * DHID * 4);
  float* x2    = (float*)alloc((size_t)NNODES * DHID * 4);
  float* inv1  = (float*)alloc((size_t)NNODES * 4);
  float* inv2  = (float*)alloc((size_t)NNODES * 4);
  int*   rp1   = (int*)alloc((size_t)(NNODES + 1) * 4);
  int*   rp2   = (int*)alloc((size_t)(NNODES + 1) * 4);
  int*   col1  = (int*)alloc((size_t)NEDGES * 4);
  int*   col2  = (int*)alloc((size_t)NEDGES * 4);
  int*   H     = (int*)alloc((size_t)HLEN * 4);
  int*   boffG = (int*)alloc((size_t)(2 * NBK + 1) * 4);
  // staging overlays x2: 2E*8 = 12.8 MB <= 25.6 MB, dead before agnn writes x2
  int2*  st    = (int2*)x2;
  float* x3    = x1;   // x1 dead after layer1 -> reuse

  const int WB = (NNODES + 3) / 4;   // 4 waves (nodes) per 256-thread block

  // CSR for both views (reused by both layers); no global atomics, segments
  // sorted in LDS -> fully deterministic across replays.
  hist_part_kernel<<<2 * PPART, 256, 0, stream>>>(dst1, dst2, H);
  scan_h_kernel<<<1, 1024, 0, stream>>>(H, boffG);
  scatter_part_kernel<<<2 * PPART, 256, 0, stream>>>(src1, dst1, src2, dst2, H, st);
  build_buckets_kernel<<<2 * NBK, 256, 0, stream>>>(st, boffG, rp1, rp2, col1, col2);

  fc1_kernel<<<NNODES / 16, 256, 0, stream>>>(X, W1, b1, x1, inv1);

  agnn_layer_kernel<<<WB, 256, 0, stream>>>(x1, inv1, rp1, col1, rp2, col2,
                                            beta1, order_attn, x2, inv2, NNODES);
  agnn_layer_kernel<<<WB, 256, 0, stream>>>(x2, inv2, rp1, col1, rp2, col2,
                                            beta2, order_attn, x3, nullptr, NNODES);

  fc2_kernel<<<NNODES / 8, 320, 0, stream>>>(x3, W2, b2, out);
}

// Round 6
// 420.960 us; speedup vs baseline: 2.2743x; 1.3768x over previous
//
#include <hip/hip_runtime.h>
#include <math.h>

#define NNODES 50000
#define NEDGES 800000
#define DIN    256
#define DHID   128
#define NCLS   40

#define BW    128                    // dst values per bucket
#define NBK   391                    // ceil(NNODES / BW)
#define CAP   6144                   // LDS col capacity per bucket (mean 2048, sd ~45)
#define PPART 128                    // partition blocks per view
#define CHUNK 6250                   // NEDGES / PPART

// ---------------- fc1: x1 = relu(X @ W1 + b1) + fused row-norm ---------------
__global__ __launch_bounds__(256) void fc1_kernel(
    const float* __restrict__ X, const float* __restrict__ W1,
    const float* __restrict__ b1, float* __restrict__ x1,
    float* __restrict__ inv1)
{
  __shared__ float Xs[16][DIN];      // 16 KB
  __shared__ float ssrow[16];
  const int tid   = threadIdx.x;
  const int node0 = blockIdx.x * 16;

  if (tid < 16) ssrow[tid] = 0.f;
  const float4* Xv  = (const float4*)(X + (size_t)node0 * DIN);
  float4*       Xsv = (float4*)(&Xs[0][0]);
#pragma unroll
  for (int t = 0; t < 4; ++t) Xsv[tid + t * 256] = Xv[tid + t * 256];
  __syncthreads();

  const int h  = tid & 127;
  const int tm = tid >> 7;           // 0..1 -> node groups of 8
  float acc[8];
#pragma unroll
  for (int r = 0; r < 8; ++r) acc[r] = 0.f;

  for (int k = 0; k < DIN; k += 4) {
    const float w0 = W1[(k + 0) * DHID + h];
    const float w1 = W1[(k + 1) * DHID + h];
    const float w2 = W1[(k + 2) * DHID + h];
    const float w3 = W1[(k + 3) * DHID + h];
#pragma unroll
    for (int r = 0; r < 8; ++r) {
      const float4 xv = *(const float4*)&Xs[tm * 8 + r][k];   // ds_read_b128 broadcast
      acc[r] += xv.x * w0 + xv.y * w1 + xv.z * w2 + xv.w * w3;
    }
  }
  const float bb   = b1[h];
  const int   lane = tid & 63;
#pragma unroll
  for (int r = 0; r < 8; ++r) {
    float v = acc[r] + bb;
    v = v > 0.f ? v : 0.f;
    x1[(size_t)(node0 + tm * 8 + r) * DHID + h] = v;
    float q = v * v;                 // fused norm: reduce over 128 cols (2 waves)
#pragma unroll
    for (int off = 32; off; off >>= 1) q += __shfl_xor(q, off);
    if (lane == 0) atomicAdd(&ssrow[tm * 8 + r], q);   // exactly 2 adds/row: commutative
  }
  __syncthreads();
  if (tid < 16) inv1[node0 + tid] = 1.0f / fmaxf(sqrtf(ssrow[tid]), 1e-12f);
}

// ---------------- fc2: out = x3 @ W2 + b2, 8 nodes/block (320 thr) -----------
__global__ __launch_bounds__(320) void fc2_kernel(
    const float* __restrict__ x3, const float* __restrict__ W2,
    const float* __restrict__ b2, float* __restrict__ out)
{
  __shared__ float Xs[8][DHID];      // 4 KB
  const int tid   = threadIdx.x;
  const int node0 = blockIdx.x * 8;
  for (int idx = tid; idx < 8 * DHID; idx += 320)
    Xs[idx >> 7][idx & 127] = x3[(size_t)node0 * DHID + idx];
  __syncthreads();

  const int ns = tid / NCLS;         // 0..7
  const int c  = tid - ns * NCLS;    // 0..39
  float acc = b2[c];
#pragma unroll 8
  for (int k = 0; k < DHID; ++k) acc += Xs[ns][k] * W2[k * NCLS + c];
  out[(size_t)(node0 + ns) * NCLS + c] = acc;
}

// ---------------- CSR build: deterministic two-pass multi-split --------------
// K1: per-(view,block) LDS histogram of a private edge chunk -> H[v][bkt][blk]
__global__ __launch_bounds__(256) void hist_part_kernel(
    const int* __restrict__ dst1, const int* __restrict__ dst2,
    int* __restrict__ H)
{
  const int bid = blockIdx.x;
  const int v   = bid >= PPART;
  const int p   = v ? bid - PPART : bid;
  const int* __restrict__ dst = v ? dst2 : dst1;

  __shared__ int hist[NBK];
  for (int i = threadIdx.x; i < NBK; i += 256) hist[i] = 0;
  __syncthreads();
  const int beg = p * CHUNK;
  const int end = (beg + CHUNK < NEDGES) ? beg + CHUNK : NEDGES;
  for (int j = beg + threadIdx.x; j < end; j += 256)
    atomicAdd(&hist[dst[j] >> 7], 1);
  __syncthreads();
  for (int i = threadIdx.x; i < NBK; i += 256)
    H[(v * NBK + i) * PPART + p] = hist[i];
}

// K2a: per-bucket exclusive scan of its 128 partition counts (in place) + total
__global__ __launch_bounds__(128) void scan_bucket_kernel(
    int* __restrict__ H, int* __restrict__ btot)
{
  const int b   = blockIdx.x;        // 0..2*NBK-1
  const int tid = threadIdx.x;
  __shared__ int sm[PPART];
  const int v = H[b * PPART + tid];
  sm[tid] = v;
  __syncthreads();
  for (int off = 1; off < PPART; off <<= 1) {
    int t = (tid >= off) ? sm[tid - off] : 0;
    __syncthreads();
    sm[tid] += t;
    __syncthreads();
  }
  H[b * PPART + tid] = sm[tid] - v;  // exclusive within bucket
  if (tid == PPART - 1) btot[b] = sm[tid];
}

// K2b: scan 2*NBK bucket totals -> boffG (global bucket bases)
__global__ __launch_bounds__(1024) void scan_btot_kernel(
    const int* __restrict__ btot, int* __restrict__ boffG)
{
  __shared__ int sm[1024];
  const int tid = threadIdx.x;
  const int v = (tid < 2 * NBK) ? btot[tid] : 0;
  sm[tid] = v;
  __syncthreads();
  for (int off = 1; off < 1024; off <<= 1) {
    int t = (tid >= off) ? sm[tid - off] : 0;
    __syncthreads();
    sm[tid] += t;
    __syncthreads();
  }
  if (tid < 2 * NBK) boffG[tid] = sm[tid] - v;
  if (tid == 0) boffG[2 * NBK] = 2 * NEDGES;
}

// K3: place edges at exact positions (LDS cursors only; writes cluster ~128B)
__global__ __launch_bounds__(256) void scatter_part_kernel(
    const int* __restrict__ src1, const int* __restrict__ dst1,
    const int* __restrict__ src2, const int* __restrict__ dst2,
    const int* __restrict__ H, const int* __restrict__ boffG,
    int2* __restrict__ st)
{
  const int bid = blockIdx.x;
  const int v   = bid >= PPART;
  const int p   = v ? bid - PPART : bid;
  const int* __restrict__ src = v ? src2 : src1;
  const int* __restrict__ dst = v ? dst2 : dst1;

  __shared__ int lcur[NBK];
  for (int i = threadIdx.x; i < NBK; i += 256)
    lcur[i] = boffG[v * NBK + i] + H[(v * NBK + i) * PPART + p];
  __syncthreads();
  const int beg = p * CHUNK;
  const int end = (beg + CHUNK < NEDGES) ? beg + CHUNK : NEDGES;
  for (int j = beg + threadIdx.x; j < end; j += 256) {
    const int s = src[j], d = dst[j];
    const int k = atomicAdd(&lcur[d >> 7], 1);
    st[k] = make_int2(s, d);
  }
}

// K4: per bucket: degrees -> rp, place srcs in LDS, sort segments (determinism),
//     coalesced col write.
__global__ __launch_bounds__(256) void build_buckets_kernel(
    const int2* __restrict__ st, const int* __restrict__ boffG,
    int* __restrict__ rp1, int* __restrict__ rp2,
    int* __restrict__ col1, int* __restrict__ col2)
{
  const int bid = blockIdx.x;
  const int v   = bid >= NBK;
  const int b   = v ? bid - NBK : bid;
  int* __restrict__ rp  = v ? rp2 : rp1;
  int* __restrict__ col = v ? col2 : col1;
  const int tid = threadIdx.x;

  const int off0G  = boffG[bid];
  const int cnt    = boffG[bid + 1] - off0G;
  const int off0   = off0G - v * NEDGES;    // view-local offset
  const int base_d = b * BW;
  const int nd     = (NNODES - base_d < BW) ? (NNODES - base_d) : BW;

  __shared__ int deg[BW];
  __shared__ int loff[BW + 1];
  __shared__ int cur[BW];
  __shared__ int lcol[CAP];

  if (tid < BW) deg[tid] = 0;
  __syncthreads();
  for (int j = tid; j < cnt; j += 256)
    atomicAdd(&deg[st[off0G + j].y - base_d], 1);
  __syncthreads();

  if (tid == 0) loff[0] = 0;
  if (tid < BW) loff[tid + 1] = deg[tid];
  __syncthreads();
  for (int off = 1; off < BW; off <<= 1) {
    int t = (tid < BW && tid + 1 >= off) ? loff[tid + 1 - off] : 0;
    __syncthreads();
    if (tid < BW && tid + 1 >= off) loff[tid + 1] += t;
    __syncthreads();
  }
  if (tid < nd) rp[base_d + tid] = off0 + loff[tid];
  if (tid == 0 && b == NBK - 1) rp[NNODES] = NEDGES;
  if (tid < BW) cur[tid] = loff[tid];
  __syncthreads();

  if (cnt <= CAP) {
    for (int j = tid; j < cnt; j += 256) {
      const int2 pr = st[off0G + j];
      const int k = atomicAdd(&cur[pr.y - base_d], 1);
      lcol[k] = pr.x;
    }
    __syncthreads();
    if (tid < nd) {                   // sort own segment ascending (in LDS)
      const int s0 = loff[tid], s1 = s0 + deg[tid];
      for (int a = s0 + 1; a < s1; ++a) {
        const int key = lcol[a];
        int c = a - 1;
        while (c >= s0 && lcol[c] > key) { lcol[c + 1] = lcol[c]; --c; }
        lcol[c + 1] = key;
      }
    }
    __syncthreads();
    for (int j = tid; j < cnt; j += 256) col[off0 + j] = lcol[j];
  } else {                            // overflow fallback (never for random data)
    for (int j = tid; j < cnt; j += 256) {
      const int2 pr = st[off0G + j];
      const int k = atomicAdd(&cur[pr.y - base_d], 1);
      col[off0 + k] = pr.x;
    }
    __syncthreads();
    if (tid < nd) {
      const int s0 = off0 + loff[tid], s1 = s0 + deg[tid];
      for (int a = s0 + 1; a < s1; ++a) {
        const int key = col[a];
        int c = a - 1;
        while (c >= s0 && col[c] > key) { col[c + 1] = col[c]; --c; }
        col[c + 1] = key;
      }
    }
  }
}

// ---------------- AGNN layer: wave/node, 4 edges in flight (16-lane groups) --
// softmax shift-invariance: w = exp(e) directly (|e| <= |beta|), identical to
// the reference's max-subtracted softmax up to fp32 rounding. Optionally fuses
// the output row-norm (inv_out) for the next layer.
__global__ __launch_bounds__(256) void agnn_layer_kernel(
    const float* __restrict__ x, const float* __restrict__ inv,
    const int* __restrict__ rp1, const int* __restrict__ col1,
    const int* __restrict__ rp2, const int* __restrict__ col2,
    const float* __restrict__ beta_p, const float* __restrict__ order_attn,
    float* __restrict__ y_out, float* __restrict__ inv_out, int n)
{
  const int wid  = (blockIdx.x * blockDim.x + threadIdx.x) >> 6;
  if (wid >= n) return;
  const int lane = threadIdx.x & 63;
  const int grp  = lane >> 4;        // 0..3  : which edge of the 4 in flight
  const int sub  = lane & 15;        // 0..15 : 8 dims each -> 128 dims

  const float beta = beta_p[0];
  const float bi   = beta * inv[wid];

  const float* xd_p = x + (size_t)wid * DHID + sub * 8;
  const float4 xd0 = *(const float4*)(xd_p);
  const float4 xd1 = *(const float4*)(xd_p + 4);

  float acc[8];
#pragma unroll
  for (int k = 0; k < 8; ++k) acc[k] = 0.f;

#pragma unroll
  for (int view = 0; view < 2; ++view) {
    const int*  rp   = view ? rp2 : rp1;
    const int*  col  = view ? col2 : col1;
    const float coef = order_attn[view];
    const int beg = rp[wid], end = rp[wid + 1];

    float s = 0.f;
    float yv[8];
#pragma unroll
    for (int k = 0; k < 8; ++k) yv[k] = 0.f;

    for (int j = beg + grp; j < end; j += 4) {
      const int   sa  = col[j];
      const float isa = inv[sa];
      const float* xs_p = x + (size_t)sa * DHID + sub * 8;
      const float4 a0 = *(const float4*)(xs_p);
      const float4 a1 = *(const float4*)(xs_p + 4);

      float d = a0.x * xd0.x + a0.y * xd0.y + a0.z * xd0.z + a0.w * xd0.w
              + a1.x * xd1.x + a1.y * xd1.y + a1.z * xd1.z + a1.w * xd1.w;
      d += __shfl_xor(d, 1);
      d += __shfl_xor(d, 2);
      d += __shfl_xor(d, 4);
      d += __shfl_xor(d, 8);

      const float w = __expf(bi * isa * d);
      s += w;
      yv[0] += w * a0.x; yv[1] += w * a0.y; yv[2] += w * a0.z; yv[3] += w * a0.w;
      yv[4] += w * a1.x; yv[5] += w * a1.y; yv[6] += w * a1.z; yv[7] += w * a1.w;
    }

    // merge the 4 group-partials (groups differ in lane bits 4..5)
    s += __shfl_xor(s, 16);
    s += __shfl_xor(s, 32);
#pragma unroll
    for (int k = 0; k < 8; ++k) {
      yv[k] += __shfl_xor(yv[k], 16);
      yv[k] += __shfl_xor(yv[k], 32);
    }
    if (end > beg) {
      const float r = coef / fmaxf(s, 1e-12f);
#pragma unroll
      for (int k = 0; k < 8; ++k) acc[k] += r * yv[k];
    }
  }

  if (inv_out) {                     // fused row-norm of the output row
    float ss = 0.f;
#pragma unroll
    for (int k = 0; k < 8; ++k) ss += acc[k] * acc[k];
    ss += __shfl_xor(ss, 1);
    ss += __shfl_xor(ss, 2);
    ss += __shfl_xor(ss, 4);
    ss += __shfl_xor(ss, 8);
    if (lane == 0) inv_out[wid] = 1.0f / fmaxf(sqrtf(ss), 1e-12f);
  }

  if (grp == 0) {
    float* yp = y_out + (size_t)wid * DHID + sub * 8;
    *(float4*)(yp)     = make_float4(acc[0], acc[1], acc[2], acc[3]);
    *(float4*)(yp + 4) = make_float4(acc[4], acc[5], acc[6], acc[7]);
  }
}

// ---------------- launcher ----------------------------------------------------
extern "C" void kernel_launch(void* const* d_in, const int* in_sizes, int n_in,
                              void* d_out, int out_size, void* d_ws, size_t ws_size,
                              hipStream_t stream)
{
  const float* X          = (const float*)d_in[0];
  const int*   src1       = (const int*)d_in[1];
  const int*   dst1       = (const int*)d_in[2];
  const int*   src2       = (const int*)d_in[3];
  const int*   dst2       = (const int*)d_in[4];
  const float* order_attn = (const float*)d_in[5];
  const float* W1         = (const float*)d_in[6];
  const float* b1         = (const float*)d_in[7];
  const float* W2         = (const float*)d_in[8];
  const float* b2         = (const float*)d_in[9];
  const float* beta1      = (const float*)d_in[10];
  const float* beta2      = (const float*)d_in[11];
  float*       out        = (float*)d_out;

  char*  ws  = (char*)d_ws;
  size_t off = 0;
  auto alloc = [&](size_t bytes) -> void* {
    void* p = ws + off;
    off += (bytes + 255) & ~size_t(255);
    return p;
  };
  float* x1    = (float*)alloc((size_t)NNODES * DHID * 4);
  float* x2    = (float*)alloc((size_t)NNODES * DHID * 4);
  float* inv1  = (float*)alloc((size_t)NNODES * 4);
  float* inv2  = (float*)alloc((size_t)NNODES * 4);
  int*   rp1   = (int*)alloc((size_t)(NNODES + 1) * 4);
  int*   rp2   = (int*)alloc((size_t)(NNODES + 1) * 4);
  int*   col1  = (int*)alloc((size_t)NEDGES * 4);
  int*   col2  = (int*)alloc((size_t)NEDGES * 4);
  int*   H     = (int*)alloc((size_t)2 * NBK * PPART * 4);
  int*   btot  = (int*)alloc((size_t)2 * NBK * 4);
  int*   boffG = (int*)alloc((size_t)(2 * NBK + 1) * 4);
  // staging overlays x2: 2E*8 = 12.8 MB <= 25.6 MB, dead before agnn writes x2
  int2*  st    = (int2*)x2;
  float* x3    = x1;   // x1 dead after layer1 -> reuse

  const int WB = (NNODES + 3) / 4;   // 4 waves (nodes) per 256-thread block

  // CSR for both views (reused by both layers); no global atomics, segments
  // sorted in LDS -> fully deterministic across replays.
  hist_part_kernel<<<2 * PPART, 256, 0, stream>>>(dst1, dst2, H);
  scan_bucket_kernel<<<2 * NBK, 128, 0, stream>>>(H, btot);
  scan_btot_kernel<<<1, 1024, 0, stream>>>(btot, boffG);
  scatter_part_kernel<<<2 * PPART, 256, 0, stream>>>(src1, dst1, src2, dst2,
                                                     H, boffG, st);
  build_buckets_kernel<<<2 * NBK, 256, 0, stream>>>(st, boffG, rp1, rp2, col1, col2);

  fc1_kernel<<<NNODES / 16, 256, 0, stream>>>(X, W1, b1, x1, inv1);

  agnn_layer_kernel<<<WB, 256, 0, stream>>>(x1, inv1, rp1, col1, rp2, col2,
                                            beta1, order_attn, x2, inv2, NNODES);
  agnn_layer_kernel<<<WB, 256, 0, stream>>>(x2, inv2, rp1, col1, rp2, col2,
                                            beta2, order_attn, x3, nullptr, NNODES);

  fc2_kernel<<<NNODES / 8, 320, 0, stream>>>(x3, W2, b2, out);
}